// Round 2
// baseline (289.638 us; speedup 1.0000x reference)
//
#include <hip/hip_runtime.h>

// Weighted MSE loss:
//   bin i s.t. edge[i] < t <= edge[i+1]  -> weight[i]; outside -> 0
//   loss = sum(w * (p - t)^2) / sum(weights)
// Memory-bound: 2 x 128MB fp32 streamed reads. float4 loads, grid-stride,
// wave64 shuffle reduce, one atomicAdd per block.

__global__ void wmse_zero_kernel(float* out, int n) {
    int i = blockIdx.x * blockDim.x + threadIdx.x;
    if (i < n) out[i] = 0.0f;
}

__device__ __forceinline__ float wmse_elem(float p, float t,
                                           float e0, float e1, float e2,
                                           float e3, float e4, float e5,
                                           float w0, float w1, float w2,
                                           float w3, float w4) {
    float w = 0.0f;
    w = (t > e0 && t <= e1) ? w0 : w;
    w = (t > e1 && t <= e2) ? w1 : w;
    w = (t > e2 && t <= e3) ? w2 : w;
    w = (t > e3 && t <= e4) ? w3 : w;
    w = (t > e4 && t <= e5) ? w4 : w;
    float d = p - t;
    return w * d * d;
}

__global__ __launch_bounds__(256) void WeightedMSELoss_60335700574782_kernel(
    const float* __restrict__ pred, const float* __restrict__ targ,
    const float* __restrict__ weights, const float* __restrict__ edge,
    float* __restrict__ out, long long n) {
    const float e0 = edge[0], e1 = edge[1], e2 = edge[2];
    const float e3 = edge[3], e4 = edge[4], e5 = edge[5];
    const float w0 = weights[0], w1 = weights[1], w2 = weights[2];
    const float w3 = weights[3], w4 = weights[4];
    const float inv_wsum = 1.0f / (w0 + w1 + w2 + w3 + w4);

    const long long n4 = n >> 2;            // float4 chunks
    const long long tid = (long long)blockIdx.x * blockDim.x + threadIdx.x;
    const long long stride = (long long)gridDim.x * blockDim.x;

    const float4* __restrict__ p4 = (const float4*)pred;
    const float4* __restrict__ t4 = (const float4*)targ;

    float acc = 0.0f;
    for (long long i = tid; i < n4; i += stride) {
        float4 p = p4[i];
        float4 t = t4[i];
        acc += wmse_elem(p.x, t.x, e0, e1, e2, e3, e4, e5, w0, w1, w2, w3, w4);
        acc += wmse_elem(p.y, t.y, e0, e1, e2, e3, e4, e5, w0, w1, w2, w3, w4);
        acc += wmse_elem(p.z, t.z, e0, e1, e2, e3, e4, e5, w0, w1, w2, w3, w4);
        acc += wmse_elem(p.w, t.w, e0, e1, e2, e3, e4, e5, w0, w1, w2, w3, w4);
    }
    // scalar tail (N not multiple of 4)
    for (long long i = (n4 << 2) + tid; i < n; i += stride) {
        acc += wmse_elem(pred[i], targ[i], e0, e1, e2, e3, e4, e5, w0, w1, w2, w3, w4);
    }

    // wave64 reduce
    #pragma unroll
    for (int off = 32; off > 0; off >>= 1)
        acc += __shfl_down(acc, off, 64);

    __shared__ float smem[4];  // 256 threads = 4 waves
    const int lane = threadIdx.x & 63;
    const int wid = threadIdx.x >> 6;
    if (lane == 0) smem[wid] = acc;
    __syncthreads();
    if (threadIdx.x == 0) {
        float bsum = smem[0] + smem[1] + smem[2] + smem[3];
        atomicAdd(out, bsum * inv_wsum);
    }
}

extern "C" void kernel_launch(void* const* d_in, const int* in_sizes, int n_in,
                              void* d_out, int out_size, void* d_ws, size_t ws_size,
                              hipStream_t stream) {
    const float* pred    = (const float*)d_in[0];
    const float* targ    = (const float*)d_in[1];
    const float* weights = (const float*)d_in[2];
    const float* edge    = (const float*)d_in[3];
    float* out = (float*)d_out;
    const long long n = (long long)in_sizes[0];

    // d_out is re-poisoned to 0xAA before every launch -> zero it first.
    wmse_zero_kernel<<<1, 64, 0, stream>>>(out, out_size);

    const int block = 256;
    long long n4 = n >> 2;
    int grid = (int)((n4 + block - 1) / block);
    if (grid > 2048) grid = 2048;   // 256 CU x 8 blocks: grid-stride the rest
    if (grid < 1) grid = 1;
    WeightedMSELoss_60335700574782_kernel<<<grid, block, 0, stream>>>(
        pred, targ, weights, edge, out, n);
}

// Round 4
// 284.613 us; speedup vs baseline: 1.0177x; 1.0177x over previous
//
#include <hip/hip_runtime.h>

// Weighted MSE loss:
//   bin i s.t. edge[i] < t <= edge[i+1]  -> weight[i]; outside -> 0
//   loss = sum(w * (p - t)^2) / sum(weights)
// Latency-bound fix (R2): manual 4x unroll -> 8 float4 loads in flight/wave,
// 4 independent accumulators, int32 indexing. Grid 2048, block 256.

__global__ void wmse_zero_kernel(float* out, int n) {
    int i = blockIdx.x * blockDim.x + threadIdx.x;
    if (i < n) out[i] = 0.0f;
}

__device__ __forceinline__ float wmse_elem(float p, float t,
                                           float e0, float e1, float e2,
                                           float e3, float e4, float e5,
                                           float w0, float w1, float w2,
                                           float w3, float w4) {
    float w = 0.0f;
    w = (t > e0 && t <= e1) ? w0 : w;
    w = (t > e1 && t <= e2) ? w1 : w;
    w = (t > e2 && t <= e3) ? w2 : w;
    w = (t > e3 && t <= e4) ? w3 : w;
    w = (t > e4 && t <= e5) ? w4 : w;
    float d = p - t;
    return w * d * d;
}

#define WMSE4(p, t) (                                                          \
    wmse_elem((p).x, (t).x, e0, e1, e2, e3, e4, e5, w0, w1, w2, w3, w4) +      \
    wmse_elem((p).y, (t).y, e0, e1, e2, e3, e4, e5, w0, w1, w2, w3, w4) +      \
    wmse_elem((p).z, (t).z, e0, e1, e2, e3, e4, e5, w0, w1, w2, w3, w4) +      \
    wmse_elem((p).w, (t).w, e0, e1, e2, e3, e4, e5, w0, w1, w2, w3, w4))

__global__ __launch_bounds__(256) void WeightedMSELoss_60335700574782_kernel(
    const float* __restrict__ pred, const float* __restrict__ targ,
    const float* __restrict__ weights, const float* __restrict__ edge,
    float* __restrict__ out, long long n) {
    const float e0 = edge[0], e1 = edge[1], e2 = edge[2];
    const float e3 = edge[3], e4 = edge[4], e5 = edge[5];
    const float w0 = weights[0], w1 = weights[1], w2 = weights[2];
    const float w3 = weights[3], w4 = weights[4];
    const float inv_wsum = 1.0f / (w0 + w1 + w2 + w3 + w4);

    const int tid = blockIdx.x * blockDim.x + threadIdx.x;
    const int stride = gridDim.x * blockDim.x;        // 524288 at grid=2048
    const long long n4 = n >> 2;                      // float4 chunks (2^23)

    const float4* __restrict__ p4 = (const float4*)pred;
    const float4* __restrict__ t4 = (const float4*)targ;

    // main unrolled region: iters * 4 * stride float4s
    const int iters = (int)(n4 / (4LL * stride));
    const long long n4_main = (long long)iters * 4LL * stride;

    float acc0 = 0.0f, acc1 = 0.0f, acc2 = 0.0f, acc3 = 0.0f;
    int i = tid;
    for (int k = 0; k < iters; ++k) {
        // 8 loads issued before any use -> 8 outstanding per wave
        float4 pa = p4[i];
        float4 ta = t4[i];
        float4 pb = p4[i + stride];
        float4 tb = t4[i + stride];
        float4 pc = p4[i + 2 * stride];
        float4 tc = t4[i + 2 * stride];
        float4 pd = p4[i + 3 * stride];
        float4 td = t4[i + 3 * stride];
        acc0 += WMSE4(pa, ta);
        acc1 += WMSE4(pb, tb);
        acc2 += WMSE4(pc, tc);
        acc3 += WMSE4(pd, td);
        i += 4 * stride;
    }
    float acc = (acc0 + acc1) + (acc2 + acc3);

    // float4 remainder (none at this N, kept for generality)
    for (long long j = n4_main + tid; j < n4; j += stride) {
        float4 p = p4[j];
        float4 t = t4[j];
        acc += WMSE4(p, t);
    }
    // scalar tail (N not multiple of 4)
    for (long long j = (n4 << 2) + tid; j < n; j += stride) {
        acc += wmse_elem(pred[j], targ[j], e0, e1, e2, e3, e4, e5, w0, w1, w2, w3, w4);
    }

    // wave64 reduce
    #pragma unroll
    for (int off = 32; off > 0; off >>= 1)
        acc += __shfl_down(acc, off, 64);

    __shared__ float smem[4];  // 256 threads = 4 waves
    const int lane = threadIdx.x & 63;
    const int wid = threadIdx.x >> 6;
    if (lane == 0) smem[wid] = acc;
    __syncthreads();
    if (threadIdx.x == 0) {
        float bsum = smem[0] + smem[1] + smem[2] + smem[3];
        atomicAdd(out, bsum * inv_wsum);
    }
}

extern "C" void kernel_launch(void* const* d_in, const int* in_sizes, int n_in,
                              void* d_out, int out_size, void* d_ws, size_t ws_size,
                              hipStream_t stream) {
    const float* pred    = (const float*)d_in[0];
    const float* targ    = (const float*)d_in[1];
    const float* weights = (const float*)d_in[2];
    const float* edge    = (const float*)d_in[3];
    float* out = (float*)d_out;
    const long long n = (long long)in_sizes[0];

    // d_out is re-poisoned to 0xAA before every launch -> zero it first.
    wmse_zero_kernel<<<1, 64, 0, stream>>>(out, out_size);

    const int block = 256;
    int grid = 2048;   // 8 blocks/CU resident; 4x-unrolled grid-stride inside
    WeightedMSELoss_60335700574782_kernel<<<grid, block, 0, stream>>>(
        pred, targ, weights, edge, out, n);
}